// Round 1
// baseline (7546.239 us; speedup 1.0000x reference)
//
#include <hip/hip_runtime.h>
#include <hip/hip_bf16.h>
#include <climits>

#define HH 512
#define WW 512
#define CIN 32
#define NPROP 256
#define NB 8
#define NCROP 16
#define C1 64
#define C2 128
#define FLAT 2048
#define FCD 512
#define MT 2048   // NB * NPROP

// ---------------- K0: init segment stats ----------------
__global__ void init_k(int* seg_i, float* seg_f) {
    int i = blockIdx.x * 256 + threadIdx.x;   // 8192 entries each
    if (i < MT * 4) {
        int comp = i & 3;
        seg_i[i] = (comp < 2) ? INT_MAX : INT_MIN;
        seg_f[i] = 0.0f;
    }
}

// ---------------- K1: segment reduction ----------------
// 32 blocks per frame, 256 threads; per-block LDS accumulation then global atomics.
__global__ __launch_bounds__(256) void segreduce_k(const int* __restrict__ lab,
                                                   const float* __restrict__ szm,
                                                   const float* __restrict__ wtm,
                                                   int* seg_i, float* seg_f) {
    __shared__ int s_ymin[NPROP], s_xmin[NPROP], s_ymax[NPROP], s_xmax[NPROP];
    __shared__ float s_h[NPROP], s_w[NPROP], s_wt[NPROP];
    int b = blockIdx.x >> 5;
    int chunk = blockIdx.x & 31;
    int t = threadIdx.x;
    s_ymin[t] = INT_MAX; s_xmin[t] = INT_MAX;
    s_ymax[t] = INT_MIN; s_xmax[t] = INT_MIN;
    s_h[t] = 0.f; s_w[t] = 0.f; s_wt[t] = 0.f;
    __syncthreads();

    const int frame = HH * WW;          // 262144
    const int cpix = frame / 32;        // 8192 pixels per block (16 rows)
    int base = b * frame + chunk * cpix;
    for (int k = 0; k < cpix; k += 256) {
        int local = chunk * cpix + k + t;       // index within frame
        int p = base + k + t;
        int l = lab[p];
        int row = local >> 9;                   // W = 512
        int col = local & 511;
        atomicMin(&s_ymin[l], row);
        atomicMax(&s_ymax[l], row);
        atomicMin(&s_xmin[l], col);
        atomicMax(&s_xmax[l], col);
        float w = wtm[p];
        float sh = szm[2 * p + 0];
        float sw = szm[2 * p + 1];
        atomicAdd(&s_h[l], sh * w);
        atomicAdd(&s_w[l], sw * w);
        atomicAdd(&s_wt[l], w);
    }
    __syncthreads();
    int g = b * NPROP + t;
    if (s_ymin[t] != INT_MAX) atomicMin(&seg_i[4 * g + 0], s_ymin[t]);
    if (s_xmin[t] != INT_MAX) atomicMin(&seg_i[4 * g + 1], s_xmin[t]);
    if (s_ymax[t] != INT_MIN) atomicMax(&seg_i[4 * g + 2], s_ymax[t]);
    if (s_xmax[t] != INT_MIN) atomicMax(&seg_i[4 * g + 3], s_xmax[t]);
    if (s_wt[t] != 0.f) {
        atomicAdd(&seg_f[4 * g + 0], s_h[t]);
        atomicAdd(&seg_f[4 * g + 1], s_w[t]);
        atomicAdd(&seg_f[4 * g + 2], s_wt[t]);
    }
}

// ---------------- K2: build new_bboxes -> d_out[0:8192] ----------------
__global__ void boxes_k(const int* __restrict__ seg_i, const float* __restrict__ seg_f,
                        float* __restrict__ out_newbox) {
    int g = blockIdx.x * 256 + threadIdx.x;
    if (g >= MT) return;
    float y0 = (float)seg_i[4 * g + 0] * (1.0f / HH);
    float x0 = (float)seg_i[4 * g + 1] * (1.0f / WW);
    float y1 = (float)(seg_i[4 * g + 2] + 1) * (1.0f / HH);
    float x1 = (float)(seg_i[4 * g + 3] + 1) * (1.0f / WW);
    float cy = (y0 + y1) * 0.5f;
    float cx = (x0 + x1) * 0.5f;
    float den = seg_f[4 * g + 2] + 1e-8f;
    float sh = (seg_f[4 * g + 0] / den) * (1.0f / HH);
    float sw = (seg_f[4 * g + 1] / den) * (1.0f / WW);
    out_newbox[4 * g + 0] = cy - sh * 0.5f;
    out_newbox[4 * g + 1] = cx - sw * 0.5f;
    out_newbox[4 * g + 2] = cy + sh * 0.5f;
    out_newbox[4 * g + 3] = cx + sw * 0.5f;
}

// ---------------- K3: fused crop + conv1 + conv2 ----------------
// one block (256 threads) per proposal
__global__ __launch_bounds__(256) void cropconv_k(const float* __restrict__ feat,
                                                  const float* __restrict__ box,
                                                  const float* __restrict__ w1,
                                                  const float* __restrict__ b1,
                                                  const float* __restrict__ w2,
                                                  const float* __restrict__ b2,
                                                  float* __restrict__ X) {
    __shared__ float crop_s[NCROP * NCROP * CIN];   // 8192 floats, 32 KB
    __shared__ float c1_s[8 * 8 * C1];              // 4096 floats, 16 KB
    int m = blockIdx.x;
    int b = m >> 8;
    int t = threadIdx.x;
    float b0 = box[4 * m + 0];
    float bx0 = box[4 * m + 1];
    float b2v = box[4 * m + 2];
    float bx1 = box[4 * m + 3];

    // crop: bilinear sample 16x16 grid, 32 channels
    for (int e = t; e < NCROP * NCROP * CIN; e += 256) {
        int c = e & 31;
        int pt = e >> 5;
        int j = pt & 15;
        int i = pt >> 4;
        float li = (float)i / 15.0f;
        float lj = (float)j / 15.0f;
        float py = (b0 + (b2v - b0) * li) * 511.0f;
        float px = (bx0 + (bx1 - bx0) * lj) * 511.0f;
        py = fminf(fmaxf(py, 0.0f), 511.0f);
        px = fminf(fmaxf(px, 0.0f), 511.0f);
        int yi = (int)floorf(py);
        int xi = (int)floorf(px);
        yi = min(max(yi, 0), 510);
        xi = min(max(xi, 0), 510);
        float fy = py - (float)yi;
        float fx = px - (float)xi;
        const float* f00 = feat + (((size_t)b * HH + yi) * WW + xi) * CIN + c;
        float v00 = f00[0];
        float v01 = f00[CIN];
        float v10 = f00[WW * CIN];
        float v11 = f00[WW * CIN + CIN];
        crop_s[e] = v00 * (1.f - fy) * (1.f - fx) + v01 * (1.f - fy) * fx
                  + v10 * fy * (1.f - fx) + v11 * fy * fx;
    }
    __syncthreads();

    // conv1: 16x16x32 -> 8x8x64, stride 2, SAME (pad_lo=0, pad_hi=1), relu
    for (int e = t; e < 8 * 8 * C1; e += 256) {
        int oc = e & 63;
        int pix = e >> 6;
        int ox = pix & 7;
        int oy = pix >> 3;
        float acc = b1[oc];
        for (int ky = 0; ky < 3; ky++) {
            int iy = oy * 2 + ky;
            if (iy >= 16) continue;
            for (int kx = 0; kx < 3; kx++) {
                int ix = ox * 2 + kx;
                if (ix >= 16) continue;
                const float* cs = crop_s + (iy * 16 + ix) * CIN;
                const float* wp = w1 + ((ky * 3 + kx) * CIN) * C1 + oc;
                #pragma unroll
                for (int ic = 0; ic < CIN; ic++) acc += cs[ic] * wp[ic * C1];
            }
        }
        c1_s[e] = fmaxf(acc, 0.0f);
    }
    __syncthreads();

    // conv2: 8x8x64 -> 4x4x128, stride 2, SAME (pad_lo=0, pad_hi=1), relu; flatten
    float* xo = X + (size_t)m * FLAT;
    for (int e = t; e < 4 * 4 * C2; e += 256) {
        int oc = e & 127;
        int pix = e >> 7;
        int ox = pix & 3;
        int oy = pix >> 2;
        float acc = b2[oc];
        for (int ky = 0; ky < 3; ky++) {
            int iy = oy * 2 + ky;
            if (iy >= 8) continue;
            for (int kx = 0; kx < 3; kx++) {
                int ix = ox * 2 + kx;
                if (ix >= 8) continue;
                const float* cs = c1_s + (iy * 8 + ix) * C1;
                const float* wp = w2 + ((ky * 3 + kx) * C1) * C2 + oc;
                #pragma unroll
                for (int ic = 0; ic < C1; ic++) acc += cs[ic] * wp[ic * C2];
            }
        }
        xo[e] = fmaxf(acc, 0.0f);   // flat idx = (oy*4+ox)*128 + oc matches reshape
    }
}

// ---------------- K4/K5: tiled fp32 GEMM + bias + relu ----------------
// Y[M,N] = act(A[M,K] @ W[K,N] + bias); 64x64 block tile, 256 threads, 4x4 per thread
template <int RELU>
__global__ __launch_bounds__(256) void gemm_bias_relu(const float* __restrict__ A,
                                                      const float* __restrict__ W,
                                                      const float* __restrict__ bias,
                                                      float* __restrict__ Y,
                                                      int M, int K, int N) {
    __shared__ float As[64][17];
    __shared__ float Ws[16][64];
    int t = threadIdx.x;
    int tx = t & 15;
    int ty = t >> 4;
    int row0 = blockIdx.y * 64;
    int col0 = blockIdx.x * 64;
    float acc[4][4] = {};
    for (int kk = 0; kk < K; kk += 16) {
        {   // A tile: 64 rows x 16 k
            int r = t >> 2;
            int k4 = (t & 3) << 2;
            const float4 v = *(const float4*)(A + (size_t)(row0 + r) * K + kk + k4);
            As[r][k4 + 0] = v.x; As[r][k4 + 1] = v.y;
            As[r][k4 + 2] = v.z; As[r][k4 + 3] = v.w;
        }
        {   // W tile: 16 k x 64 cols
            int kw = t >> 4;
            int c4 = (t & 15) << 2;
            *(float4*)&Ws[kw][c4] = *(const float4*)(W + (size_t)(kk + kw) * N + col0 + c4);
        }
        __syncthreads();
        #pragma unroll
        for (int k = 0; k < 16; k++) {
            float a0 = As[ty * 4 + 0][k];
            float a1 = As[ty * 4 + 1][k];
            float a2 = As[ty * 4 + 2][k];
            float a3 = As[ty * 4 + 3][k];
            float4 bv = *(float4*)&Ws[k][tx * 4];
            acc[0][0] += a0 * bv.x; acc[0][1] += a0 * bv.y; acc[0][2] += a0 * bv.z; acc[0][3] += a0 * bv.w;
            acc[1][0] += a1 * bv.x; acc[1][1] += a1 * bv.y; acc[1][2] += a1 * bv.z; acc[1][3] += a1 * bv.w;
            acc[2][0] += a2 * bv.x; acc[2][1] += a2 * bv.y; acc[2][2] += a2 * bv.z; acc[2][3] += a2 * bv.w;
            acc[3][0] += a3 * bv.x; acc[3][1] += a3 * bv.y; acc[3][2] += a3 * bv.z; acc[3][3] += a3 * bv.w;
        }
        __syncthreads();
    }
    for (int i = 0; i < 4; i++) {
        int r = row0 + ty * 4 + i;
        for (int j = 0; j < 4; j++) {
            int c = col0 + tx * 4 + j;
            float v = acc[i][j] + bias[c];
            if (RELU) v = fmaxf(v, 0.0f);
            Y[(size_t)r * N + c] = v;
        }
    }
}

// ---------------- K6: reg/score heads ----------------
__global__ void heads_k(const float* __restrict__ Y2,
                        const float* __restrict__ regw, const float* __restrict__ regb,
                        const float* __restrict__ scw, const float* __restrict__ scb,
                        float* __restrict__ regsc) {
    int idx = blockIdx.x * 256 + threadIdx.x;
    int m = idx >> 4;
    int j = idx & 15;
    if (m >= MT || j >= 15) return;
    const float* y = Y2 + (size_t)m * FCD;
    float s = 0.0f;
    if (j < 12) {
        for (int k = 0; k < FCD; k++) s += y[k] * regw[k * 12 + j];
        regsc[m * 16 + j] = s + regb[j];
    } else {
        int c = j - 12;
        for (int k = 0; k < FCD; k++) s += y[k] * scw[k * 3 + c];
        regsc[m * 16 + j] = s + scb[c];
    }
}

// ---------------- K7: class gather + recover boxes ----------------
__global__ void finalize_k(const float* __restrict__ regsc, const int* __restrict__ cls,
                           float* __restrict__ out) {
    int m = blockIdx.x * 256 + threadIdx.x;
    if (m >= MT) return;
    int c = cls[m >> 8];
    float r0 = regsc[m * 16 + c * 4 + 0];
    float r1 = regsc[m * 16 + c * 4 + 1];
    float r2 = regsc[m * 16 + c * 4 + 2];
    float r3 = regsc[m * 16 + c * 4 + 3];
    float sc = regsc[m * 16 + 12 + c];
    float* reg_out = out + 8192;     // [M,4]
    float* sc_out  = out + 16384;    // [M]
    float* rb_out  = out + 18432;    // [M,4]
    reg_out[4 * m + 0] = r0;
    reg_out[4 * m + 1] = r1;
    reg_out[4 * m + 2] = r2;
    reg_out[4 * m + 3] = r3;
    sc_out[m] = sc;
    const float* nb = out;           // new_bboxes written by boxes_k
    float v0 = nb[4 * m + 0], v1 = nb[4 * m + 1], v2 = nb[4 * m + 2], v3 = nb[4 * m + 3];
    float bh = v2 - v0, bw = v3 - v1;
    float bcy = (v0 + v2) * 0.5f, bcx = (v1 + v3) * 0.5f;
    float ncy = bcy + r0 * bh;
    float ncx = bcx + r1 * bw;
    float nh = bh * expf(r2);
    float nw = bw * expf(r3);
    rb_out[4 * m + 0] = ncy - nh * 0.5f;
    rb_out[4 * m + 1] = ncx - nw * 0.5f;
    rb_out[4 * m + 2] = ncy + nh * 0.5f;
    rb_out[4 * m + 3] = ncx + nw * 0.5f;
}

extern "C" void kernel_launch(void* const* d_in, const int* in_sizes, int n_in,
                              void* d_out, int out_size, void* d_ws, size_t ws_size,
                              hipStream_t stream) {
    const float* feat = (const float*)d_in[0];
    const int*   lab  = (const int*)d_in[1];
    const float* szm  = (const float*)d_in[2];
    const float* wtm  = (const float*)d_in[3];
    const int*   cls  = (const int*)d_in[4];
    const float* w1   = (const float*)d_in[5];
    const float* b1   = (const float*)d_in[6];
    const float* w2   = (const float*)d_in[7];
    const float* b2   = (const float*)d_in[8];
    const float* fc1w = (const float*)d_in[9];
    const float* fc1b = (const float*)d_in[10];
    const float* fc2w = (const float*)d_in[11];
    const float* fc2b = (const float*)d_in[12];
    const float* regw = (const float*)d_in[13];
    const float* regb = (const float*)d_in[14];
    const float* scw  = (const float*)d_in[15];
    const float* scb  = (const float*)d_in[16];
    float* out = (float*)d_out;

    float* ws = (float*)d_ws;
    int*   seg_i = (int*)ws;                       // 2048*4 ints
    float* seg_f = ws + 8192;                      // 2048*4 floats
    float* X     = ws + 16384;                     // 2048*2048
    float* Y1    = X + (size_t)MT * FLAT;          // 2048*512
    float* Y2    = Y1 + (size_t)MT * FCD;          // 2048*512
    float* regsc = Y2 + (size_t)MT * FCD;          // 2048*16

    init_k<<<32, 256, 0, stream>>>(seg_i, seg_f);
    segreduce_k<<<NB * 32, 256, 0, stream>>>(lab, szm, wtm, seg_i, seg_f);
    boxes_k<<<MT / 256, 256, 0, stream>>>(seg_i, seg_f, out);
    cropconv_k<<<MT, 256, 0, stream>>>(feat, out, w1, b1, w2, b2, X);
    dim3 g1(FCD / 64, MT / 64);
    gemm_bias_relu<1><<<g1, 256, 0, stream>>>(X, fc1w, fc1b, Y1, MT, FLAT, FCD);
    gemm_bias_relu<1><<<g1, 256, 0, stream>>>(Y1, fc2w, fc2b, Y2, MT, FCD, FCD);
    heads_k<<<MT * 16 / 256, 256, 0, stream>>>(Y2, regw, regb, scw, scb, regsc);
    finalize_k<<<MT / 256, 256, 0, stream>>>(regsc, cls, out);
}

// Round 4
// 813.648 us; speedup vs baseline: 9.2746x; 9.2746x over previous
//
#include <hip/hip_runtime.h>
#include <hip/hip_bf16.h>
#include <climits>

#define HH 512
#define WW 512
#define CIN 32
#define NPROP 256
#define NB 8
#define NCROP 16
#define C1 64
#define C2 128
#define FLAT 2048
#define FCD 512
#define MT 2048   // NB * NPROP

// ---------------- K0: init segment stats ----------------
__global__ void init_k(int* seg_i, float* seg_f) {
    int i = blockIdx.x * 256 + threadIdx.x;   // 8192 entries each
    if (i < MT * 4) {
        int comp = i & 3;
        seg_i[i] = (comp < 2) ? INT_MAX : INT_MIN;
        seg_f[i] = 0.0f;
    }
}

// ---------------- K1: segment reduction ----------------
__global__ __launch_bounds__(256) void segreduce_k(const int* __restrict__ lab,
                                                   const float* __restrict__ szm,
                                                   const float* __restrict__ wtm,
                                                   int* seg_i, float* seg_f) {
    __shared__ int s_ymin[NPROP], s_xmin[NPROP], s_ymax[NPROP], s_xmax[NPROP];
    __shared__ float s_h[NPROP], s_w[NPROP], s_wt[NPROP];
    int b = blockIdx.x >> 5;
    int chunk = blockIdx.x & 31;
    int t = threadIdx.x;
    s_ymin[t] = INT_MAX; s_xmin[t] = INT_MAX;
    s_ymax[t] = INT_MIN; s_xmax[t] = INT_MIN;
    s_h[t] = 0.f; s_w[t] = 0.f; s_wt[t] = 0.f;
    __syncthreads();

    const int frame = HH * WW;
    const int cpix = frame / 32;        // 8192 pixels per block
    int base = b * frame + chunk * cpix;
    for (int k = 0; k < cpix; k += 256) {
        int local = chunk * cpix + k + t;
        int p = base + k + t;
        int l = lab[p];
        int row = local >> 9;
        int col = local & 511;
        atomicMin(&s_ymin[l], row);
        atomicMax(&s_ymax[l], row);
        atomicMin(&s_xmin[l], col);
        atomicMax(&s_xmax[l], col);
        float w = wtm[p];
        float sh = szm[2 * p + 0];
        float sw = szm[2 * p + 1];
        atomicAdd(&s_h[l], sh * w);
        atomicAdd(&s_w[l], sw * w);
        atomicAdd(&s_wt[l], w);
    }
    __syncthreads();
    int g = b * NPROP + t;
    if (s_ymin[t] != INT_MAX) atomicMin(&seg_i[4 * g + 0], s_ymin[t]);
    if (s_xmin[t] != INT_MAX) atomicMin(&seg_i[4 * g + 1], s_xmin[t]);
    if (s_ymax[t] != INT_MIN) atomicMax(&seg_i[4 * g + 2], s_ymax[t]);
    if (s_xmax[t] != INT_MIN) atomicMax(&seg_i[4 * g + 3], s_xmax[t]);
    if (s_wt[t] != 0.f) {
        atomicAdd(&seg_f[4 * g + 0], s_h[t]);
        atomicAdd(&seg_f[4 * g + 1], s_w[t]);
        atomicAdd(&seg_f[4 * g + 2], s_wt[t]);
    }
}

// ---------------- K2: build new_bboxes -> d_out[0:8192] ----------------
__global__ void boxes_k(const int* __restrict__ seg_i, const float* __restrict__ seg_f,
                        float* __restrict__ out_newbox) {
    int g = blockIdx.x * 256 + threadIdx.x;
    if (g >= MT) return;
    float y0 = (float)seg_i[4 * g + 0] * (1.0f / HH);
    float x0 = (float)seg_i[4 * g + 1] * (1.0f / WW);
    float y1 = (float)(seg_i[4 * g + 2] + 1) * (1.0f / HH);
    float x1 = (float)(seg_i[4 * g + 3] + 1) * (1.0f / WW);
    float cy = (y0 + y1) * 0.5f;
    float cx = (x0 + x1) * 0.5f;
    float den = seg_f[4 * g + 2] + 1e-8f;
    float sh = (seg_f[4 * g + 0] / den) * (1.0f / HH);
    float sw = (seg_f[4 * g + 1] / den) * (1.0f / WW);
    out_newbox[4 * g + 0] = cy - sh * 0.5f;
    out_newbox[4 * g + 1] = cx - sw * 0.5f;
    out_newbox[4 * g + 2] = cy + sh * 0.5f;
    out_newbox[4 * g + 3] = cx + sw * 0.5f;
}

// ---------------- K3a: fused crop + conv1 (LDS weights, per-tap staged) ----------------
// one block per proposal; 256 threads = 16 oc-quads x 16 pixel-groups
__global__ __launch_bounds__(256) void cropconv1_k(const float* __restrict__ feat,
                                                   const float* __restrict__ box,
                                                   const float* __restrict__ w1,
                                                   const float* __restrict__ b1,
                                                   float* __restrict__ c1) {
    __shared__ float crop_s[17 * 17 * CIN];   // zero-padded SAME border, 36.1 KB
    __shared__ float w_s[32 * 64];            // one 3x3-tap slice of w1, 8 KB
    int bid = blockIdx.x;
    int m = (bid & 7) * 256 + (bid >> 3);     // XCD swizzle: each XCD ~ one frame
    int b = m >> 8;
    int t = threadIdx.x;
    int q = t & 15;       // oc quad: oc = q*4+u
    int pg = t >> 4;      // pixel group: p = pg*4+pi

    // zero padded crop tile
    for (int e = t; e < 17 * 17 * CIN; e += 256) crop_s[e] = 0.0f;

    float b0 = box[4 * m + 0];
    float bx0 = box[4 * m + 1];
    float by1 = box[4 * m + 2];
    float bx1 = box[4 * m + 3];
    __syncthreads();

    // bilinear crop into interior [0..15][0..15]
    for (int e = t; e < NCROP * NCROP * CIN; e += 256) {
        int c = e & 31;
        int pt = e >> 5;
        int j = pt & 15;
        int i = pt >> 4;
        float py = (b0 + (by1 - b0) * ((float)i / 15.0f)) * 511.0f;
        float px = (bx0 + (bx1 - bx0) * ((float)j / 15.0f)) * 511.0f;
        py = fminf(fmaxf(py, 0.0f), 511.0f);
        px = fminf(fmaxf(px, 0.0f), 511.0f);
        int yi = (int)floorf(py);
        int xi = (int)floorf(px);
        yi = min(max(yi, 0), 510);
        xi = min(max(xi, 0), 510);
        float fy = py - (float)yi;
        float fx = px - (float)xi;
        const float* f00 = feat + (((size_t)b * HH + yi) * WW + xi) * CIN + c;
        float v00 = f00[0];
        float v01 = f00[CIN];
        float v10 = f00[WW * CIN];
        float v11 = f00[WW * CIN + CIN];
        crop_s[(i * 17 + j) * CIN + c] =
            v00 * (1.f - fy) * (1.f - fx) + v01 * (1.f - fy) * fx
          + v10 * fy * (1.f - fx) + v11 * fy * fx;
    }

    float acc[4][4] = {};
    int oy[4], ox[4];
    #pragma unroll
    for (int pi = 0; pi < 4; pi++) {
        int p = pg * 4 + pi;
        oy[pi] = p >> 3;
        ox[pi] = p & 7;
    }

    for (int tap = 0; tap < 9; tap++) {
        int ky = tap / 3, kx = tap % 3;
        __syncthreads();   // protect w_s reads of previous tap (and crop writes at tap 0)
        for (int e = t; e < 2048; e += 256) w_s[e] = w1[tap * 2048 + e];
        __syncthreads();
        #pragma unroll
        for (int ic4 = 0; ic4 < 8; ic4++) {
            float4 wv0 = *(float4*)&w_s[(ic4 * 4 + 0) * 64 + q * 4];
            float4 wv1 = *(float4*)&w_s[(ic4 * 4 + 1) * 64 + q * 4];
            float4 wv2 = *(float4*)&w_s[(ic4 * 4 + 2) * 64 + q * 4];
            float4 wv3 = *(float4*)&w_s[(ic4 * 4 + 3) * 64 + q * 4];
            #pragma unroll
            for (int pi = 0; pi < 4; pi++) {
                int iy = oy[pi] * 2 + ky;
                int ix = ox[pi] * 2 + kx;
                float4 av = *(float4*)&crop_s[(iy * 17 + ix) * CIN + ic4 * 4];
                acc[pi][0] += av.x * wv0.x + av.y * wv1.x + av.z * wv2.x + av.w * wv3.x;
                acc[pi][1] += av.x * wv0.y + av.y * wv1.y + av.z * wv2.y + av.w * wv3.y;
                acc[pi][2] += av.x * wv0.z + av.y * wv1.z + av.z * wv2.z + av.w * wv3.z;
                acc[pi][3] += av.x * wv0.w + av.y * wv1.w + av.z * wv2.w + av.w * wv3.w;
            }
        }
    }

    float4 bv = *(const float4*)&b1[q * 4];
    #pragma unroll
    for (int pi = 0; pi < 4; pi++) {
        int p = pg * 4 + pi;
        float4 o;
        o.x = fmaxf(acc[pi][0] + bv.x, 0.f);
        o.y = fmaxf(acc[pi][1] + bv.y, 0.f);
        o.z = fmaxf(acc[pi][2] + bv.z, 0.f);
        o.w = fmaxf(acc[pi][3] + bv.w, 0.f);
        *(float4*)&c1[((size_t)m * 64 + p) * 64 + q * 4] = o;
    }
}

// ---------------- K3b: conv2 as per-tap GEMM over 4 proposals ----------------
// block: 4 proposals -> M=64 rows (4x16 pix), N=128 oc, K=9 taps x 64 ic
__global__ __launch_bounds__(256) void conv2_k(const float* __restrict__ c1,
                                               const float* __restrict__ w2,
                                               const float* __restrict__ b2,
                                               float* __restrict__ X) {
    __shared__ float A_s[64 * 68];   // [ic][row(64)+pad4], 17.4 KB
    __shared__ float W_s[64 * 128];  // one tap slice, 32 KB
    int bid = blockIdx.x;
    int blk = (bid & 7) * 64 + (bid >> 3);   // XCD swizzle (512 blocks)
    int prop0 = blk * 4;
    int t = threadIdx.x;
    int tx = t & 15;     // col0 = tx*8
    int ty = t >> 4;     // row0 = ty*4
    float acc[4][8] = {};

    int r = t >> 2;      // staging row 0..63
    int icq = t & 3;     // ic 16-group
    int s_prop = prop0 + (r >> 4);
    int s_pix = r & 15;
    int s_oy = s_pix >> 2, s_ox = s_pix & 3;

    for (int tap = 0; tap < 9; tap++) {
        int ky = tap / 3, kx = tap % 3;
        __syncthreads();
        // stage W tap slice [64 ic][128 oc] (contiguous in w2)
        for (int e = t; e < 2048; e += 256)
            ((float4*)W_s)[e] = ((const float4*)w2)[tap * 2048 + e];
        // stage A tap tile transposed: A_s[ic][row]
        {
            int iy = s_oy * 2 + ky;
            int ix = s_ox * 2 + kx;
            bool valid = (iy < 8) && (ix < 8);
            const float* src = c1 + (((size_t)s_prop * 8 + iy) * 8 + ix) * 64 + icq * 16;
            #pragma unroll
            for (int u = 0; u < 4; u++) {
                float4 v = valid ? *(const float4*)&src[u * 4]
                                 : make_float4(0.f, 0.f, 0.f, 0.f);
                A_s[(icq * 16 + u * 4 + 0) * 68 + r] = v.x;
                A_s[(icq * 16 + u * 4 + 1) * 68 + r] = v.y;
                A_s[(icq * 16 + u * 4 + 2) * 68 + r] = v.z;
                A_s[(icq * 16 + u * 4 + 3) * 68 + r] = v.w;
            }
        }
        __syncthreads();
        #pragma unroll 8
        for (int k = 0; k < 64; k++) {
            float4 a = *(float4*)&A_s[k * 68 + ty * 4];
            float4 w0 = *(float4*)&W_s[k * 128 + tx * 8];
            float4 w1v = *(float4*)&W_s[k * 128 + tx * 8 + 4];
            #pragma unroll
            for (int i = 0; i < 4; i++) {
                float av = (i == 0) ? a.x : (i == 1) ? a.y : (i == 2) ? a.z : a.w;
                acc[i][0] += av * w0.x; acc[i][1] += av * w0.y;
                acc[i][2] += av * w0.z; acc[i][3] += av * w0.w;
                acc[i][4] += av * w1v.x; acc[i][5] += av * w1v.y;
                acc[i][6] += av * w1v.z; acc[i][7] += av * w1v.w;
            }
        }
    }

    float4 bv0 = *(const float4*)&b2[tx * 8];
    float4 bv1 = *(const float4*)&b2[tx * 8 + 4];
    #pragma unroll
    for (int i = 0; i < 4; i++) {
        int row = ty * 4 + i;
        int prop = prop0 + (row >> 4);
        int pix = row & 15;
        float* dst = X + ((size_t)prop * 16 + pix) * 128 + tx * 8;
        float4 o0, o1;
        o0.x = fmaxf(acc[i][0] + bv0.x, 0.f);
        o0.y = fmaxf(acc[i][1] + bv0.y, 0.f);
        o0.z = fmaxf(acc[i][2] + bv0.z, 0.f);
        o0.w = fmaxf(acc[i][3] + bv0.w, 0.f);
        o1.x = fmaxf(acc[i][4] + bv1.x, 0.f);
        o1.y = fmaxf(acc[i][5] + bv1.y, 0.f);
        o1.z = fmaxf(acc[i][6] + bv1.z, 0.f);
        o1.w = fmaxf(acc[i][7] + bv1.w, 0.f);
        *(float4*)&dst[0] = o0;
        *(float4*)&dst[4] = o1;
    }
}

// ---------------- K4/K5: tiled fp32 GEMM + bias + relu ----------------
template <int RELU>
__global__ __launch_bounds__(256) void gemm_bias_relu(const float* __restrict__ A,
                                                      const float* __restrict__ W,
                                                      const float* __restrict__ bias,
                                                      float* __restrict__ Y,
                                                      int M, int K, int N) {
    __shared__ float As[64][17];
    __shared__ float Ws[16][64];
    int t = threadIdx.x;
    int tx = t & 15;
    int ty = t >> 4;
    int row0 = blockIdx.y * 64;
    int col0 = blockIdx.x * 64;
    float acc[4][4] = {};
    for (int kk = 0; kk < K; kk += 16) {
        {
            int r = t >> 2;
            int k4 = (t & 3) << 2;
            const float4 v = *(const float4*)(A + (size_t)(row0 + r) * K + kk + k4);
            As[r][k4 + 0] = v.x; As[r][k4 + 1] = v.y;
            As[r][k4 + 2] = v.z; As[r][k4 + 3] = v.w;
        }
        {
            int kw = t >> 4;
            int c4 = (t & 15) << 2;
            *(float4*)&Ws[kw][c4] = *(const float4*)(W + (size_t)(kk + kw) * N + col0 + c4);
        }
        __syncthreads();
        #pragma unroll
        for (int k = 0; k < 16; k++) {
            float a0 = As[ty * 4 + 0][k];
            float a1 = As[ty * 4 + 1][k];
            float a2 = As[ty * 4 + 2][k];
            float a3 = As[ty * 4 + 3][k];
            float4 bv = *(float4*)&Ws[k][tx * 4];
            acc[0][0] += a0 * bv.x; acc[0][1] += a0 * bv.y; acc[0][2] += a0 * bv.z; acc[0][3] += a0 * bv.w;
            acc[1][0] += a1 * bv.x; acc[1][1] += a1 * bv.y; acc[1][2] += a1 * bv.z; acc[1][3] += a1 * bv.w;
            acc[2][0] += a2 * bv.x; acc[2][1] += a2 * bv.y; acc[2][2] += a2 * bv.z; acc[2][3] += a2 * bv.w;
            acc[3][0] += a3 * bv.x; acc[3][1] += a3 * bv.y; acc[3][2] += a3 * bv.z; acc[3][3] += a3 * bv.w;
        }
        __syncthreads();
    }
    for (int i = 0; i < 4; i++) {
        int r = row0 + ty * 4 + i;
        for (int j = 0; j < 4; j++) {
            int c = col0 + tx * 4 + j;
            float v = acc[i][j] + bias[c];
            if (RELU) v = fmaxf(v, 0.0f);
            Y[(size_t)r * N + c] = v;
        }
    }
}

// ---------------- K6: reg/score heads ----------------
__global__ void heads_k(const float* __restrict__ Y2,
                        const float* __restrict__ regw, const float* __restrict__ regb,
                        const float* __restrict__ scw, const float* __restrict__ scb,
                        float* __restrict__ regsc) {
    int idx = blockIdx.x * 256 + threadIdx.x;
    int m = idx >> 4;
    int j = idx & 15;
    if (m >= MT || j >= 15) return;
    const float* y = Y2 + (size_t)m * FCD;
    float s = 0.0f;
    if (j < 12) {
        for (int k = 0; k < FCD; k++) s += y[k] * regw[k * 12 + j];
        regsc[m * 16 + j] = s + regb[j];
    } else {
        int c = j - 12;
        for (int k = 0; k < FCD; k++) s += y[k] * scw[k * 3 + c];
        regsc[m * 16 + j] = s + scb[c];
    }
}

// ---------------- K7: class gather + recover boxes ----------------
__global__ void finalize_k(const float* __restrict__ regsc, const int* __restrict__ cls,
                           float* __restrict__ out) {
    int m = blockIdx.x * 256 + threadIdx.x;
    if (m >= MT) return;
    int c = cls[m >> 8];
    float r0 = regsc[m * 16 + c * 4 + 0];
    float r1 = regsc[m * 16 + c * 4 + 1];
    float r2 = regsc[m * 16 + c * 4 + 2];
    float r3 = regsc[m * 16 + c * 4 + 3];
    float sc = regsc[m * 16 + 12 + c];
    float* reg_out = out + 8192;
    float* sc_out  = out + 16384;
    float* rb_out  = out + 18432;
    reg_out[4 * m + 0] = r0;
    reg_out[4 * m + 1] = r1;
    reg_out[4 * m + 2] = r2;
    reg_out[4 * m + 3] = r3;
    sc_out[m] = sc;
    const float* nb = out;
    float v0 = nb[4 * m + 0], v1 = nb[4 * m + 1], v2 = nb[4 * m + 2], v3 = nb[4 * m + 3];
    float bh = v2 - v0, bw = v3 - v1;
    float bcy = (v0 + v2) * 0.5f, bcx = (v1 + v3) * 0.5f;
    float ncy = bcy + r0 * bh;
    float ncx = bcx + r1 * bw;
    float nh = bh * expf(r2);
    float nw = bw * expf(r3);
    rb_out[4 * m + 0] = ncy - nh * 0.5f;
    rb_out[4 * m + 1] = ncx - nw * 0.5f;
    rb_out[4 * m + 2] = ncy + nh * 0.5f;
    rb_out[4 * m + 3] = ncx + nw * 0.5f;
}

extern "C" void kernel_launch(void* const* d_in, const int* in_sizes, int n_in,
                              void* d_out, int out_size, void* d_ws, size_t ws_size,
                              hipStream_t stream) {
    const float* feat = (const float*)d_in[0];
    const int*   lab  = (const int*)d_in[1];
    const float* szm  = (const float*)d_in[2];
    const float* wtm  = (const float*)d_in[3];
    const int*   cls  = (const int*)d_in[4];
    const float* w1   = (const float*)d_in[5];
    const float* b1   = (const float*)d_in[6];
    const float* w2   = (const float*)d_in[7];
    const float* b2   = (const float*)d_in[8];
    const float* fc1w = (const float*)d_in[9];
    const float* fc1b = (const float*)d_in[10];
    const float* fc2w = (const float*)d_in[11];
    const float* fc2b = (const float*)d_in[12];
    const float* regw = (const float*)d_in[13];
    const float* regb = (const float*)d_in[14];
    const float* scw  = (const float*)d_in[15];
    const float* scb  = (const float*)d_in[16];
    float* out = (float*)d_out;

    float* ws = (float*)d_ws;
    int*   seg_i = (int*)ws;                       // 2048*4 ints
    float* seg_f = ws + 8192;                      // 2048*4 floats
    float* c1    = ws + 16384;                     // 2048*64*64 = 8.39M floats
    float* X     = c1 + (size_t)MT * 64 * 64;      // 2048*2048 = 4.19M floats
    // after conv2_k, c1 is dead -> alias FC buffers onto it
    float* Y1    = c1;                             // 2048*512
    float* Y2    = c1 + (size_t)MT * FCD;          // 2048*512
    float* regsc = c1 + (size_t)2 * MT * FCD;      // 2048*16

    init_k<<<32, 256, 0, stream>>>(seg_i, seg_f);
    segreduce_k<<<NB * 32, 256, 0, stream>>>(lab, szm, wtm, seg_i, seg_f);
    boxes_k<<<MT / 256, 256, 0, stream>>>(seg_i, seg_f, out);
    cropconv1_k<<<MT, 256, 0, stream>>>(feat, out, w1, b1, c1);
    conv2_k<<<MT / 4, 256, 0, stream>>>(c1, w2, b2, X);
    dim3 g1(FCD / 64, MT / 64);
    gemm_bias_relu<1><<<g1, 256, 0, stream>>>(X, fc1w, fc1b, Y1, MT, FLAT, FCD);
    gemm_bias_relu<1><<<g1, 256, 0, stream>>>(Y1, fc2w, fc2b, Y2, MT, FCD, FCD);
    heads_k<<<MT * 16 / 256, 256, 0, stream>>>(Y2, regw, regb, scw, scb, regsc);
    finalize_k<<<MT / 256, 256, 0, stream>>>(regsc, cls, out);
}

// Round 5
// 708.868 us; speedup vs baseline: 10.6455x; 1.1478x over previous
//
#include <hip/hip_runtime.h>
#include <hip/hip_bf16.h>
#include <climits>

#define HH 512
#define WW 512
#define CIN 32
#define NPROP 256
#define NB 8
#define NCROP 16
#define C1 64
#define C2 128
#define FLAT 2048
#define FCD 512
#define MT 2048   // NB * NPROP

typedef __attribute__((ext_vector_type(8))) short bf16x8;   // 8 bf16 = 4 VGPR
typedef __attribute__((ext_vector_type(4))) short short4v;  // 8B LDS read
typedef __attribute__((ext_vector_type(4))) float f32x4;    // MFMA acc

__device__ __forceinline__ short f2bf(float x) {            // RNE fp32->bf16
    unsigned u = __float_as_uint(x);
    unsigned r = (u + 0x7FFFu + ((u >> 16) & 1u)) >> 16;
    return (short)r;
}
__device__ __forceinline__ float bf2f(short h) {
    return __uint_as_float(((unsigned)(unsigned short)h) << 16);
}
__device__ __forceinline__ unsigned pk(short a, short b) {
    return (unsigned)(unsigned short)a | ((unsigned)(unsigned short)b << 16);
}
__device__ __forceinline__ bf16x8 ld8(const short* p) {     // two 8B LDS reads
    short4v a = *(const short4v*)p;
    short4v b = *(const short4v*)(p + 4);
    bf16x8 r = {a[0], a[1], a[2], a[3], b[0], b[1], b[2], b[3]};
    return r;
}
__device__ __forceinline__ f32x4 mfma16(bf16x8 a, bf16x8 b, f32x4 c) {
    return __builtin_amdgcn_mfma_f32_16x16x32_bf16(a, b, c, 0, 0, 0);
}

// ---------------- K0: init segment stats ----------------
__global__ void init_k(int* seg_i, float* seg_f) {
    int i = blockIdx.x * 256 + threadIdx.x;
    if (i < MT * 4) {
        int comp = i & 3;
        seg_i[i] = (comp < 2) ? INT_MAX : INT_MIN;
        seg_f[i] = 0.0f;
    }
}

// ---------------- K1: segment reduction (512 blocks = 2/CU) ----------------
__global__ __launch_bounds__(256) void segreduce_k(const int* __restrict__ lab,
                                                   const float* __restrict__ szm,
                                                   const float* __restrict__ wtm,
                                                   int* seg_i, float* seg_f) {
    __shared__ int s_ymin[NPROP], s_xmin[NPROP], s_ymax[NPROP], s_xmax[NPROP];
    __shared__ float s_h[NPROP], s_w[NPROP], s_wt[NPROP];
    int b = blockIdx.x >> 6;
    int chunk = blockIdx.x & 63;
    int t = threadIdx.x;
    s_ymin[t] = INT_MAX; s_xmin[t] = INT_MAX;
    s_ymax[t] = INT_MIN; s_xmax[t] = INT_MIN;
    s_h[t] = 0.f; s_w[t] = 0.f; s_wt[t] = 0.f;
    __syncthreads();

    const int frame = HH * WW;
    const int cpix = frame / 64;        // 4096 pixels per block
    int base = b * frame + chunk * cpix;
    for (int k = 0; k < cpix; k += 256) {
        int local = chunk * cpix + k + t;
        int p = base + k + t;
        int l = lab[p];
        int row = local >> 9;
        int col = local & 511;
        atomicMin(&s_ymin[l], row);
        atomicMax(&s_ymax[l], row);
        atomicMin(&s_xmin[l], col);
        atomicMax(&s_xmax[l], col);
        float w = wtm[p];
        float2 sv = *(const float2*)&szm[2 * p];
        atomicAdd(&s_h[l], sv.x * w);
        atomicAdd(&s_w[l], sv.y * w);
        atomicAdd(&s_wt[l], w);
    }
    __syncthreads();
    int g = b * NPROP + t;
    if (s_ymin[t] != INT_MAX) atomicMin(&seg_i[4 * g + 0], s_ymin[t]);
    if (s_xmin[t] != INT_MAX) atomicMin(&seg_i[4 * g + 1], s_xmin[t]);
    if (s_ymax[t] != INT_MIN) atomicMax(&seg_i[4 * g + 2], s_ymax[t]);
    if (s_xmax[t] != INT_MIN) atomicMax(&seg_i[4 * g + 3], s_xmax[t]);
    if (s_wt[t] != 0.f) {
        atomicAdd(&seg_f[4 * g + 0], s_h[t]);
        atomicAdd(&seg_f[4 * g + 1], s_w[t]);
        atomicAdd(&seg_f[4 * g + 2], s_wt[t]);
    }
}

// ---------------- K2: build new_bboxes -> d_out[0:8192] ----------------
__global__ void boxes_k(const int* __restrict__ seg_i, const float* __restrict__ seg_f,
                        float* __restrict__ out_newbox) {
    int g = blockIdx.x * 256 + threadIdx.x;
    if (g >= MT) return;
    float y0 = (float)seg_i[4 * g + 0] * (1.0f / HH);
    float x0 = (float)seg_i[4 * g + 1] * (1.0f / WW);
    float y1 = (float)(seg_i[4 * g + 2] + 1) * (1.0f / HH);
    float x1 = (float)(seg_i[4 * g + 3] + 1) * (1.0f / WW);
    float cy = (y0 + y1) * 0.5f;
    float cx = (x0 + x1) * 0.5f;
    float den = seg_f[4 * g + 2] + 1e-8f;
    float sh = (seg_f[4 * g + 0] / den) * (1.0f / HH);
    float sw = (seg_f[4 * g + 1] / den) * (1.0f / WW);
    out_newbox[4 * g + 0] = cy - sh * 0.5f;
    out_newbox[4 * g + 1] = cx - sw * 0.5f;
    out_newbox[4 * g + 2] = cy + sh * 0.5f;
    out_newbox[4 * g + 3] = cx + sw * 0.5f;
}

// ---------------- K3a: fused crop + conv1 (bf16x3 MFMA) ----------------
// one block/proposal, 4 waves; wave w computes pix [16w,16w+16) x 64 oc.
// crop stored directly as bf16 hi/lo in LDS; pixel stride 36 (bank spread).
__global__ __launch_bounds__(256) void cropconv1_k(const float* __restrict__ feat,
                                                   const float* __restrict__ box,
                                                   const float* __restrict__ w1,
                                                   const float* __restrict__ b1,
                                                   float* __restrict__ c1) {
    __shared__ __align__(16) short cropH[17 * 17 * 36];   // 20.8 KB
    __shared__ __align__(16) short cropL[17 * 17 * 36];   // 20.8 KB
    __shared__ __align__(16) short w1tH[64 * 40];         // 5 KB, [oc][ic] pad40
    __shared__ __align__(16) short w1tL[64 * 40];         // 5 KB
    int bid = blockIdx.x;
    int m = (bid & 7) * 256 + (bid >> 3);     // XCD swizzle
    int b = m >> 8;
    int t = threadIdx.x;
    int wave = t >> 6;
    int lane = t & 63;
    int lrow = lane & 15;
    int lk8 = (lane >> 4) * 8;

    for (int e = t; e < 17 * 17 * 36; e += 256) { cropH[e] = 0; cropL[e] = 0; }

    float by0 = box[4 * m + 0];
    float bx0 = box[4 * m + 1];
    float by1 = box[4 * m + 2];
    float bx1 = box[4 * m + 3];
    __syncthreads();

    // bilinear crop into interior [0..15][0..15], bf16 hi/lo split
    for (int e = t; e < NCROP * NCROP * CIN; e += 256) {
        int c = e & 31;
        int pt = e >> 5;
        int j = pt & 15;
        int i = pt >> 4;
        float py = (by0 + (by1 - by0) * ((float)i / 15.0f)) * 511.0f;
        float px = (bx0 + (bx1 - bx0) * ((float)j / 15.0f)) * 511.0f;
        py = fminf(fmaxf(py, 0.0f), 511.0f);
        px = fminf(fmaxf(px, 0.0f), 511.0f);
        int yi = (int)floorf(py);
        int xi = (int)floorf(px);
        yi = min(max(yi, 0), 510);
        xi = min(max(xi, 0), 510);
        float fy = py - (float)yi;
        float fx = px - (float)xi;
        const float* f00 = feat + (((size_t)b * HH + yi) * WW + xi) * CIN + c;
        float v00 = f00[0];
        float v01 = f00[CIN];
        float v10 = f00[WW * CIN];
        float v11 = f00[WW * CIN + CIN];
        float val = v00 * (1.f - fy) * (1.f - fx) + v01 * (1.f - fy) * fx
                  + v10 * fy * (1.f - fx) + v11 * fy * fx;
        int d = (i * 17 + j) * 36 + c;
        short h = f2bf(val);
        cropH[d] = h;
        cropL[d] = f2bf(val - bf2f(h));
    }

    int apix = wave * 16 + lrow;       // A-supply row (this lane's pixel)
    int aoy = apix >> 3, aox = apix & 7;
    f32x4 acc[4] = {};                 // 4 oc-tiles of 16

    int soc = t & 63;                  // w1^T staging: oc
    int sic0 = (t >> 6) * 8;           // 8 ic per thread

    for (int tap = 0; tap < 9; tap++) {
        int ky = tap / 3, kx = tap % 3;
        __syncthreads();               // prev-tap frag reads done
        #pragma unroll
        for (int jj = 0; jj < 8; jj += 2) {
            float x0 = w1[tap * 2048 + (sic0 + jj) * 64 + soc];
            float x1 = w1[tap * 2048 + (sic0 + jj + 1) * 64 + soc];
            short h0 = f2bf(x0), h1 = f2bf(x1);
            short l0 = f2bf(x0 - bf2f(h0)), l1 = f2bf(x1 - bf2f(h1));
            *(unsigned*)&w1tH[soc * 40 + sic0 + jj] = pk(h0, h1);
            *(unsigned*)&w1tL[soc * 40 + sic0 + jj] = pk(l0, l1);
        }
        __syncthreads();
        int iy = aoy * 2 + ky, ix = aox * 2 + kx;   // SAME pad rows/cols are zeros
        bf16x8 ah = ld8(&cropH[(iy * 17 + ix) * 36 + lk8]);
        bf16x8 al = ld8(&cropL[(iy * 17 + ix) * 36 + lk8]);
        #pragma unroll
        for (int ni = 0; ni < 4; ni++) {
            bf16x8 bh = ld8(&w1tH[(ni * 16 + lrow) * 40 + lk8]);
            bf16x8 bl = ld8(&w1tL[(ni * 16 + lrow) * 40 + lk8]);
            acc[ni] = mfma16(al, bh, acc[ni]);
            acc[ni] = mfma16(ah, bl, acc[ni]);
            acc[ni] = mfma16(ah, bh, acc[ni]);
        }
    }
    int prow = wave * 16 + (lane >> 4) * 4;   // C/D: row=(lane>>4)*4+r, col=lane&15
    #pragma unroll
    for (int ni = 0; ni < 4; ni++) {
        int oc = ni * 16 + lrow;
        float bv = b1[oc];
        #pragma unroll
        for (int r = 0; r < 4; r++) {
            float v = acc[ni][r] + bv;
            c1[((size_t)m * 64 + prow + r) * 64 + oc] = fmaxf(v, 0.f);
        }
    }
}

// ---------------- K3b: conv2 as im2col bf16x3 MFMA GEMM ----------------
// M=32768 (prop*16+pix), N=128, K=576 (tap*64+ic). BM=128, BN=64, BK=32.
__global__ __launch_bounds__(256) void conv2gemm_k(const float* __restrict__ c1,
                                                   const float* __restrict__ w2,
                                                   const float* __restrict__ b2,
                                                   float* __restrict__ X) {
    __shared__ __align__(16) short Ah[128 * 40], Al[128 * 40];
    __shared__ __align__(16) short Wh[64 * 40], Wl[64 * 40];
    int t = threadIdx.x;
    int row0 = blockIdx.y * 128;
    int col0 = blockIdx.x * 64;
    int wave = t >> 6, lane = t & 63;
    int wr = wave >> 1, wc = wave & 1;
    int lrow = lane & 15, lk8 = (lane >> 4) * 8;
    f32x4 acc[4][2] = {};

    int srow = t >> 1;                 // A staging: row, 16 k per thread
    int sk0 = (t & 1) * 16;
    int grow = row0 + srow;
    int prop = grow >> 4, pix = grow & 15;
    int oy = pix >> 2, ox = pix & 3;
    int wn = t & 63, wk0 = (t >> 6) * 8;   // W^T staging

    for (int kk = 0; kk < 576; kk += 32) {
        int tap = kk >> 6;
        int ky = tap / 3, kx = tap % 3;
        int ichalf = (kk >> 5) & 1;
        int iy = oy * 2 + ky, ix = ox * 2 + kx;
        bool valid = (iy < 8) && (ix < 8);
        const float* ap = c1 + ((size_t)(prop * 64 + iy * 8 + ix)) * 64 + ichalf * 32 + sk0;
        #pragma unroll
        for (int j4 = 0; j4 < 4; j4++) {
            float4 v = valid ? *(const float4*)(ap + j4 * 4)
                             : make_float4(0.f, 0.f, 0.f, 0.f);
            short h0 = f2bf(v.x), h1 = f2bf(v.y), h2 = f2bf(v.z), h3 = f2bf(v.w);
            short l0 = f2bf(v.x - bf2f(h0)), l1 = f2bf(v.y - bf2f(h1));
            short l2 = f2bf(v.z - bf2f(h2)), l3 = f2bf(v.w - bf2f(h3));
            int d = srow * 40 + sk0 + j4 * 4;
            *(unsigned*)&Ah[d] = pk(h0, h1); *(unsigned*)&Ah[d + 2] = pk(h2, h3);
            *(unsigned*)&Al[d] = pk(l0, l1); *(unsigned*)&Al[d + 2] = pk(l2, l3);
        }
        #pragma unroll
        for (int jj = 0; jj < 8; jj += 2) {
            float x0 = w2[(size_t)(kk + wk0 + jj) * 128 + col0 + wn];
            float x1 = w2[(size_t)(kk + wk0 + jj + 1) * 128 + col0 + wn];
            short h0 = f2bf(x0), h1 = f2bf(x1);
            short l0 = f2bf(x0 - bf2f(h0)), l1 = f2bf(x1 - bf2f(h1));
            *(unsigned*)&Wh[wn * 40 + wk0 + jj] = pk(h0, h1);
            *(unsigned*)&Wl[wn * 40 + wk0 + jj] = pk(l0, l1);
        }
        __syncthreads();
        bf16x8 bh[2], bl[2];
        #pragma unroll
        for (int ni = 0; ni < 2; ni++) {
            int n = wc * 32 + ni * 16 + lrow;
            bh[ni] = ld8(&Wh[n * 40 + lk8]);
            bl[ni] = ld8(&Wl[n * 40 + lk8]);
        }
        #pragma unroll
        for (int mi = 0; mi < 4; mi++) {
            int rr = wr * 64 + mi * 16 + lrow;
            bf16x8 ah = ld8(&Ah[rr * 40 + lk8]);
            bf16x8 al = ld8(&Al[rr * 40 + lk8]);
            #pragma unroll
            for (int ni = 0; ni < 2; ni++) {
                acc[mi][ni] = mfma16(al, bh[ni], acc[mi][ni]);
                acc[mi][ni] = mfma16(ah, bl[ni], acc[mi][ni]);
                acc[mi][ni] = mfma16(ah, bh[ni], acc[mi][ni]);
            }
        }
        __syncthreads();
    }
    #pragma unroll
    for (int mi = 0; mi < 4; mi++) {
        int rowb = row0 + wr * 64 + mi * 16 + (lane >> 4) * 4;
        #pragma unroll
        for (int ni = 0; ni < 2; ni++) {
            int col = col0 + wc * 32 + ni * 16 + lrow;
            float bv = b2[col];
            #pragma unroll
            for (int r = 0; r < 4; r++) {
                float v = acc[mi][ni][r] + bv;
                X[(size_t)(rowb + r) * 128 + col] = fmaxf(v, 0.f);
            }
        }
    }
}

// ---------------- K4/K5: fc GEMM, bf16x3 MFMA ----------------
// Y[M,N] = relu(A[M,K] @ W[K,N] + bias). BM=128, BN=64, BK=32, 256 thr.
template <int RELU>
__global__ __launch_bounds__(256) void fcgemm_k(const float* __restrict__ A,
                                                const float* __restrict__ W,
                                                const float* __restrict__ bias,
                                                float* __restrict__ Y,
                                                int M, int K, int N) {
    __shared__ __align__(16) short Ah[128 * 40], Al[128 * 40];
    __shared__ __align__(16) short Wh[64 * 40], Wl[64 * 40];
    int t = threadIdx.x;
    int row0 = blockIdx.y * 128;
    int col0 = blockIdx.x * 64;
    int wave = t >> 6, lane = t & 63;
    int wr = wave >> 1, wc = wave & 1;
    int lrow = lane & 15, lk8 = (lane >> 4) * 8;
    f32x4 acc[4][2] = {};

    int srow = t >> 1;
    int sk0 = (t & 1) * 16;
    int wn = t & 63, wk0 = (t >> 6) * 8;

    for (int kk = 0; kk < K; kk += 32) {
        const float* ap = A + (size_t)(row0 + srow) * K + kk + sk0;
        #pragma unroll
        for (int j4 = 0; j4 < 4; j4++) {
            float4 v = *(const float4*)(ap + j4 * 4);
            short h0 = f2bf(v.x), h1 = f2bf(v.y), h2 = f2bf(v.z), h3 = f2bf(v.w);
            short l0 = f2bf(v.x - bf2f(h0)), l1 = f2bf(v.y - bf2f(h1));
            short l2 = f2bf(v.z - bf2f(h2)), l3 = f2bf(v.w - bf2f(h3));
            int d = srow * 40 + sk0 + j4 * 4;
            *(unsigned*)&Ah[d] = pk(h0, h1); *(unsigned*)&Ah[d + 2] = pk(h2, h3);
            *(unsigned*)&Al[d] = pk(l0, l1); *(unsigned*)&Al[d + 2] = pk(l2, l3);
        }
        #pragma unroll
        for (int jj = 0; jj < 8; jj += 2) {
            float x0 = W[(size_t)(kk + wk0 + jj) * N + col0 + wn];
            float x1 = W[(size_t)(kk + wk0 + jj + 1) * N + col0 + wn];
            short h0 = f2bf(x0), h1 = f2bf(x1);
            short l0 = f2bf(x0 - bf2f(h0)), l1 = f2bf(x1 - bf2f(h1));
            *(unsigned*)&Wh[wn * 40 + wk0 + jj] = pk(h0, h1);
            *(unsigned*)&Wl[wn * 40 + wk0 + jj] = pk(l0, l1);
        }
        __syncthreads();
        bf16x8 bh[2], bl[2];
        #pragma unroll
        for (int ni = 0; ni < 2; ni++) {
            int n = wc * 32 + ni * 16 + lrow;
            bh[ni] = ld8(&Wh[n * 40 + lk8]);
            bl[ni] = ld8(&Wl[n * 40 + lk8]);
        }
        #pragma unroll
        for (int mi = 0; mi < 4; mi++) {
            int rr = wr * 64 + mi * 16 + lrow;
            bf16x8 ah = ld8(&Ah[rr * 40 + lk8]);
            bf16x8 al = ld8(&Al[rr * 40 + lk8]);
            #pragma unroll
            for (int ni = 0; ni < 2; ni++) {
                acc[mi][ni] = mfma16(al, bh[ni], acc[mi][ni]);
                acc[mi][ni] = mfma16(ah, bl[ni], acc[mi][ni]);
                acc[mi][ni] = mfma16(ah, bh[ni], acc[mi][ni]);
            }
        }
        __syncthreads();
    }
    #pragma unroll
    for (int mi = 0; mi < 4; mi++) {
        int rowb = row0 + wr * 64 + mi * 16 + (lane >> 4) * 4;
        #pragma unroll
        for (int ni = 0; ni < 2; ni++) {
            int col = col0 + wc * 32 + ni * 16 + lrow;
            float bv = bias[col];
            #pragma unroll
            for (int r = 0; r < 4; r++) {
                float v = acc[mi][ni][r] + bv;
                if (RELU) v = fmaxf(v, 0.f);
                Y[(size_t)(rowb + r) * N + col] = v;
            }
        }
    }
}

// ---------------- K6: reg/score heads ----------------
__global__ void heads_k(const float* __restrict__ Y2,
                        const float* __restrict__ regw, const float* __restrict__ regb,
                        const float* __restrict__ scw, const float* __restrict__ scb,
                        float* __restrict__ regsc) {
    int idx = blockIdx.x * 256 + threadIdx.x;
    int m = idx >> 4;
    int j = idx & 15;
    if (m >= MT || j >= 15) return;
    const float* y = Y2 + (size_t)m * FCD;
    float s = 0.0f;
    if (j < 12) {
        for (int k = 0; k < FCD; k++) s += y[k] * regw[k * 12 + j];
        regsc[m * 16 + j] = s + regb[j];
    } else {
        int c = j - 12;
        for (int k = 0; k < FCD; k++) s += y[k] * scw[k * 3 + c];
        regsc[m * 16 + j] = s + scb[c];
    }
}

// ---------------- K7: class gather + recover boxes ----------------
__global__ void finalize_k(const float* __restrict__ regsc, const int* __restrict__ cls,
                           float* __restrict__ out) {
    int m = blockIdx.x * 256 + threadIdx.x;
    if (m >= MT) return;
    int c = cls[m >> 8];
    float r0 = regsc[m * 16 + c * 4 + 0];
    float r1 = regsc[m * 16 + c * 4 + 1];
    float r2 = regsc[m * 16 + c * 4 + 2];
    float r3 = regsc[m * 16 + c * 4 + 3];
    float sc = regsc[m * 16 + 12 + c];
    float* reg_out = out + 8192;
    float* sc_out  = out + 16384;
    float* rb_out  = out + 18432;
    reg_out[4 * m + 0] = r0;
    reg_out[4 * m + 1] = r1;
    reg_out[4 * m + 2] = r2;
    reg_out[4 * m + 3] = r3;
    sc_out[m] = sc;
    const float* nb = out;
    float v0 = nb[4 * m + 0], v1 = nb[4 * m + 1], v2 = nb[4 * m + 2], v3 = nb[4 * m + 3];
    float bh = v2 - v0, bw = v3 - v1;
    float bcy = (v0 + v2) * 0.5f, bcx = (v1 + v3) * 0.5f;
    float ncy = bcy + r0 * bh;
    float ncx = bcx + r1 * bw;
    float nh = bh * expf(r2);
    float nw = bw * expf(r3);
    rb_out[4 * m + 0] = ncy - nh * 0.5f;
    rb_out[4 * m + 1] = ncx - nw * 0.5f;
    rb_out[4 * m + 2] = ncy + nh * 0.5f;
    rb_out[4 * m + 3] = ncx + nw * 0.5f;
}

extern "C" void kernel_launch(void* const* d_in, const int* in_sizes, int n_in,
                              void* d_out, int out_size, void* d_ws, size_t ws_size,
                              hipStream_t stream) {
    const float* feat = (const float*)d_in[0];
    const int*   lab  = (const int*)d_in[1];
    const float* szm  = (const float*)d_in[2];
    const float* wtm  = (const float*)d_in[3];
    const int*   cls  = (const int*)d_in[4];
    const float* w1   = (const float*)d_in[5];
    const float* b1   = (const float*)d_in[6];
    const float* w2   = (const float*)d_in[7];
    const float* b2   = (const float*)d_in[8];
    const float* fc1w = (const float*)d_in[9];
    const float* fc1b = (const float*)d_in[10];
    const float* fc2w = (const float*)d_in[11];
    const float* fc2b = (const float*)d_in[12];
    const float* regw = (const float*)d_in[13];
    const float* regb = (const float*)d_in[14];
    const float* scw  = (const float*)d_in[15];
    const float* scb  = (const float*)d_in[16];
    float* out = (float*)d_out;

    float* ws = (float*)d_ws;
    int*   seg_i = (int*)ws;                       // 2048*4 ints
    float* seg_f = ws + 8192;                      // 2048*4 floats
    float* c1    = ws + 16384;                     // 2048*64*64 = 8.39M floats
    float* X     = c1 + (size_t)MT * 64 * 64;      // 2048*2048
    // after conv2gemm_k, c1 is dead -> alias FC buffers onto it
    float* Y1    = c1;                             // 2048*512
    float* Y2    = c1 + (size_t)MT * FCD;          // 2048*512
    float* regsc = c1 + (size_t)2 * MT * FCD;      // 2048*16

    init_k<<<32, 256, 0, stream>>>(seg_i, seg_f);
    segreduce_k<<<NB * 64, 256, 0, stream>>>(lab, szm, wtm, seg_i, seg_f);
    boxes_k<<<MT / 256, 256, 0, stream>>>(seg_i, seg_f, out);
    cropconv1_k<<<MT, 256, 0, stream>>>(feat, out, w1, b1, c1);
    conv2gemm_k<<<dim3(C2 / 64, MT * 16 / 128), 256, 0, stream>>>(c1, w2, b2, X);
    fcgemm_k<1><<<dim3(FCD / 64, MT / 128), 256, 0, stream>>>(X, fc1w, fc1b, Y1, MT, FLAT, FCD);
    fcgemm_k<1><<<dim3(FCD / 64, MT / 128), 256, 0, stream>>>(Y1, fc2w, fc2b, Y2, MT, FCD, FCD);
    heads_k<<<MT * 16 / 256, 256, 0, stream>>>(Y2, regw, regb, scw, scb, regsc);
    finalize_k<<<MT / 256, 256, 0, stream>>>(regsc, cls, out);
}

// Round 6
// 601.329 us; speedup vs baseline: 12.5493x; 1.1788x over previous
//
#include <hip/hip_runtime.h>
#include <hip/hip_bf16.h>
#include <climits>

#define HH 512
#define WW 512
#define CIN 32
#define NPROP 256
#define NB 8
#define NCROP 16
#define C1 64
#define C2 128
#define FLAT 2048
#define FCD 512
#define MT 2048   // NB * NPROP

typedef __attribute__((ext_vector_type(8))) short bf16x8;
typedef __attribute__((ext_vector_type(4))) short short4v;
typedef __attribute__((ext_vector_type(4))) float f32x4;

__device__ __forceinline__ short f2bf(float x) {            // RNE fp32->bf16
    unsigned u = __float_as_uint(x);
    unsigned r = (u + 0x7FFFu + ((u >> 16) & 1u)) >> 16;
    return (short)r;
}
__device__ __forceinline__ float bf2f(short h) {
    return __uint_as_float(((unsigned)(unsigned short)h) << 16);
}
__device__ __forceinline__ unsigned pk(short a, short b) {
    return (unsigned)(unsigned short)a | ((unsigned)(unsigned short)b << 16);
}
__device__ __forceinline__ bf16x8 ld8(const short* p) {
    short4v a = *(const short4v*)p;
    short4v b = *(const short4v*)(p + 4);
    bf16x8 r = {a[0], a[1], a[2], a[3], b[0], b[1], b[2], b[3]};
    return r;
}
__device__ __forceinline__ f32x4 mfma16(bf16x8 a, bf16x8 b, f32x4 c) {
    return __builtin_amdgcn_mfma_f32_16x16x32_bf16(a, b, c, 0, 0, 0);
}

// ---------------- K0: init segment stats ----------------
__global__ void init_k(int* seg_i, float* seg_f) {
    int i = blockIdx.x * 256 + threadIdx.x;
    if (i < MT * 4) {
        int comp = i & 3;
        seg_i[i] = (comp < 2) ? INT_MAX : INT_MIN;
        seg_f[i] = 0.0f;
    }
}

// ---------------- K1: segment reduction ----------------
__global__ __launch_bounds__(256) void segreduce_k(const int* __restrict__ lab,
                                                   const float* __restrict__ szm,
                                                   const float* __restrict__ wtm,
                                                   int* seg_i, float* seg_f) {
    __shared__ int s_ymin[NPROP], s_xmin[NPROP], s_ymax[NPROP], s_xmax[NPROP];
    __shared__ float s_h[NPROP], s_w[NPROP], s_wt[NPROP];
    int b = blockIdx.x >> 6;
    int chunk = blockIdx.x & 63;
    int t = threadIdx.x;
    s_ymin[t] = INT_MAX; s_xmin[t] = INT_MAX;
    s_ymax[t] = INT_MIN; s_xmax[t] = INT_MIN;
    s_h[t] = 0.f; s_w[t] = 0.f; s_wt[t] = 0.f;
    __syncthreads();

    const int frame = HH * WW;
    const int cpix = frame / 64;        // 4096 pixels per block
    int base = b * frame + chunk * cpix;
    for (int k = 0; k < cpix; k += 256) {
        int local = chunk * cpix + k + t;
        int p = base + k + t;
        int l = lab[p];
        int row = local >> 9;
        int col = local & 511;
        atomicMin(&s_ymin[l], row);
        atomicMax(&s_ymax[l], row);
        atomicMin(&s_xmin[l], col);
        atomicMax(&s_xmax[l], col);
        float w = wtm[p];
        float2 sv = *(const float2*)&szm[2 * p];
        atomicAdd(&s_h[l], sv.x * w);
        atomicAdd(&s_w[l], sv.y * w);
        atomicAdd(&s_wt[l], w);
    }
    __syncthreads();
    int g = b * NPROP + t;
    if (s_ymin[t] != INT_MAX) atomicMin(&seg_i[4 * g + 0], s_ymin[t]);
    if (s_xmin[t] != INT_MAX) atomicMin(&seg_i[4 * g + 1], s_xmin[t]);
    if (s_ymax[t] != INT_MIN) atomicMax(&seg_i[4 * g + 2], s_ymax[t]);
    if (s_xmax[t] != INT_MIN) atomicMax(&seg_i[4 * g + 3], s_xmax[t]);
    if (s_wt[t] != 0.f) {
        atomicAdd(&seg_f[4 * g + 0], s_h[t]);
        atomicAdd(&seg_f[4 * g + 1], s_w[t]);
        atomicAdd(&seg_f[4 * g + 2], s_wt[t]);
    }
}

// ---------------- K2: build new_bboxes -> d_out[0:8192] ----------------
__global__ void boxes_k(const int* __restrict__ seg_i, const float* __restrict__ seg_f,
                        float* __restrict__ out_newbox) {
    int g = blockIdx.x * 256 + threadIdx.x;
    if (g >= MT) return;
    float y0 = (float)seg_i[4 * g + 0] * (1.0f / HH);
    float x0 = (float)seg_i[4 * g + 1] * (1.0f / WW);
    float y1 = (float)(seg_i[4 * g + 2] + 1) * (1.0f / HH);
    float x1 = (float)(seg_i[4 * g + 3] + 1) * (1.0f / WW);
    float cy = (y0 + y1) * 0.5f;
    float cx = (x0 + x1) * 0.5f;
    float den = seg_f[4 * g + 2] + 1e-8f;
    float sh = (seg_f[4 * g + 0] / den) * (1.0f / HH);
    float sw = (seg_f[4 * g + 1] / den) * (1.0f / WW);
    out_newbox[4 * g + 0] = cy - sh * 0.5f;
    out_newbox[4 * g + 1] = cx - sw * 0.5f;
    out_newbox[4 * g + 2] = cy + sh * 0.5f;
    out_newbox[4 * g + 3] = cx + sw * 0.5f;
}

// ---------------- K3: bilinear crop -> bf16 hi/lo planes ----------------
// one block/proposal, no LDS; thread handles channel-pair cp, writes packed uint.
__global__ __launch_bounds__(256) void crop_k(const float* __restrict__ feat,
                                              const float* __restrict__ box,
                                              short* __restrict__ cH,
                                              short* __restrict__ cL) {
    int bid = blockIdx.x;
    int m = (bid & 7) * 256 + (bid >> 3);     // XCD swizzle: each XCD ~ one frame
    int b = m >> 8;
    int t = threadIdx.x;
    float by0 = box[4 * m + 0];
    float bx0 = box[4 * m + 1];
    float by1 = box[4 * m + 2];
    float bx1 = box[4 * m + 3];
    unsigned* dH = (unsigned*)cH + (size_t)m * 256 * 16;
    unsigned* dL = (unsigned*)cL + (size_t)m * 256 * 16;
    for (int e = t; e < 256 * 16; e += 256) {
        int cp = e & 15;          // channel pair -> ch 2cp, 2cp+1
        int pix = e >> 4;
        int j = pix & 15, i = pix >> 4;
        float py = (by0 + (by1 - by0) * ((float)i / 15.0f)) * 511.0f;
        float px = (bx0 + (bx1 - bx0) * ((float)j / 15.0f)) * 511.0f;
        py = fminf(fmaxf(py, 0.0f), 511.0f);
        px = fminf(fmaxf(px, 0.0f), 511.0f);
        int yi = (int)floorf(py);
        int xi = (int)floorf(px);
        yi = min(max(yi, 0), 510);
        xi = min(max(xi, 0), 510);
        float fy = py - (float)yi;
        float fx = px - (float)xi;
        float w00 = (1.f - fy) * (1.f - fx);
        float w01 = (1.f - fy) * fx;
        float w10 = fy * (1.f - fx);
        float w11 = fy * fx;
        const float* f00 = feat + (((size_t)b * HH + yi) * WW + xi) * CIN + cp * 2;
        float2 v00 = *(const float2*)f00;
        float2 v01 = *(const float2*)(f00 + CIN);
        float2 v10 = *(const float2*)(f00 + WW * CIN);
        float2 v11 = *(const float2*)(f00 + WW * CIN + CIN);
        float a = v00.x * w00 + v01.x * w01 + v10.x * w10 + v11.x * w11;
        float c = v00.y * w00 + v01.y * w01 + v10.y * w10 + v11.y * w11;
        short ha = f2bf(a), hc = f2bf(c);
        short la = f2bf(a - bf2f(ha)), lc = f2bf(c - bf2f(hc));
        dH[e] = pk(ha, hc);
        dL[e] = pk(la, lc);
    }
}

// ---------------- unified bf16x3 MFMA GEMM ----------------
// MODE 0: dense A[M][K] (H/L planes). MODE 1: conv1 im2col (crop planes,
// row=prop*64+opix, k=tap*32+ic). MODE 2: conv2 im2col (c1 planes,
// row=prop*16+opix, k=tap*64+ic). B: fp32 W[K][N], split per block.
// BM=BN=64, BK=32, 256 thr, 4 waves (2x2), per-wave 32x32 = acc[2][2].
template <int MODE, int OUT16>
__global__ __launch_bounds__(256) void gemm_k(const short* __restrict__ AH,
                                              const short* __restrict__ AL,
                                              const float* __restrict__ W,
                                              const float* __restrict__ bias,
                                              short* __restrict__ OH,
                                              short* __restrict__ OL,
                                              float* __restrict__ OF,
                                              int M, int K, int N) {
    __shared__ __align__(16) short Ah[64 * 36], Al[64 * 36];
    __shared__ __align__(16) short Wh[64 * 36], Wl[64 * 36];
    int t = threadIdx.x;
    int col0 = blockIdx.x * 64;
    int row0 = blockIdx.y * 64;
    int wave = t >> 6, lane = t & 63;
    int wr = wave >> 1, wc = wave & 1;
    int lrow = lane & 15, lk8 = (lane >> 4) * 8;
    f32x4 acc[2][2] = {};

    int srow = t >> 2, sk0 = (t & 3) * 8;   // A staging: 8 shorts of one row
    int wn = t & 63, wk0 = (t >> 6) * 8;    // B staging: 8 k's of one col
    int grow = row0 + srow;

    for (int kk = 0; kk < K; kk += 32) {
        // ---- A staging (16B copies from H/L planes, zero-pad for conv) ----
        const short *pH, *pL;
        bool valid = true;
        if (MODE == 0) {
            size_t off = (size_t)grow * K + kk + sk0;
            pH = AH + off; pL = AL + off;
        } else if (MODE == 1) {
            int prop = grow >> 6, opix = grow & 63;
            int oy = opix >> 3, ox = opix & 7;
            int tap = kk >> 5;
            int ky = tap / 3, kx = tap % 3;
            int iy = oy * 2 + ky, ix = ox * 2 + kx;
            valid = (iy < 16) && (ix < 16);
            size_t off = ((size_t)prop * 256 + iy * 16 + ix) * 32 + sk0;
            pH = AH + off; pL = AL + off;
        } else {
            int prop = grow >> 4, opix = grow & 15;
            int oy = opix >> 2, ox = opix & 3;
            int tap = kk >> 6;
            int ky = tap / 3, kx = tap % 3;
            int iy = oy * 2 + ky, ix = ox * 2 + kx;
            valid = (iy < 8) && (ix < 8);
            size_t off = ((size_t)prop * 64 + iy * 8 + ix) * 64 + (kk & 32) + sk0;
            pH = AH + off; pL = AL + off;
        }
        short4v z = {0, 0, 0, 0};
        int d = srow * 36 + sk0;
        *(short4v*)&Ah[d]     = valid ? *(const short4v*)pH : z;
        *(short4v*)&Ah[d + 4] = valid ? *(const short4v*)(pH + 4) : z;
        *(short4v*)&Al[d]     = valid ? *(const short4v*)pL : z;
        *(short4v*)&Al[d + 4] = valid ? *(const short4v*)(pL + 4) : z;
        // ---- B staging: fp32 -> hi/lo split ----
        #pragma unroll
        for (int jj = 0; jj < 8; jj += 2) {
            float x0 = W[(size_t)(kk + wk0 + jj) * N + col0 + wn];
            float x1 = W[(size_t)(kk + wk0 + jj + 1) * N + col0 + wn];
            short h0 = f2bf(x0), h1 = f2bf(x1);
            short l0 = f2bf(x0 - bf2f(h0)), l1 = f2bf(x1 - bf2f(h1));
            *(unsigned*)&Wh[wn * 36 + wk0 + jj] = pk(h0, h1);
            *(unsigned*)&Wl[wn * 36 + wk0 + jj] = pk(l0, l1);
        }
        __syncthreads();
        bf16x8 bh[2], bl[2], ah[2], al[2];
        #pragma unroll
        for (int ni = 0; ni < 2; ni++) {
            int n = wc * 32 + ni * 16 + lrow;
            bh[ni] = ld8(&Wh[n * 36 + lk8]);
            bl[ni] = ld8(&Wl[n * 36 + lk8]);
        }
        #pragma unroll
        for (int mi = 0; mi < 2; mi++) {
            int rr = wr * 32 + mi * 16 + lrow;
            ah[mi] = ld8(&Ah[rr * 36 + lk8]);
            al[mi] = ld8(&Al[rr * 36 + lk8]);
        }
        #pragma unroll
        for (int mi = 0; mi < 2; mi++)
            #pragma unroll
            for (int ni = 0; ni < 2; ni++) {
                acc[mi][ni] = mfma16(al[mi], bh[ni], acc[mi][ni]);
                acc[mi][ni] = mfma16(ah[mi], bl[ni], acc[mi][ni]);
                acc[mi][ni] = mfma16(ah[mi], bh[ni], acc[mi][ni]);
            }
        __syncthreads();
    }
    // ---- epilogue: bias + relu; write H/L planes or fp32 ----
    #pragma unroll
    for (int mi = 0; mi < 2; mi++) {
        int rowb = row0 + wr * 32 + mi * 16 + (lane >> 4) * 4;
        #pragma unroll
        for (int ni = 0; ni < 2; ni++) {
            int col = col0 + wc * 32 + ni * 16 + lrow;
            float bv = bias[col];
            #pragma unroll
            for (int r = 0; r < 4; r++) {
                float v = fmaxf(acc[mi][ni][r] + bv, 0.f);
                size_t o = (size_t)(rowb + r) * N + col;
                if (OUT16) {
                    short h = f2bf(v);
                    OH[o] = h;
                    OL[o] = f2bf(v - bf2f(h));
                } else {
                    OF[o] = v;
                }
            }
        }
    }
}

// ---------------- K6: heads via LDS-staged Wcat ----------------
// block = 16 m-rows; thread (ml, j): dot(Y2[m], Wcat[:,j]), j<15.
__global__ __launch_bounds__(256) void heads2_k(const float* __restrict__ Y2,
                                                const float* __restrict__ regw,
                                                const float* __restrict__ regb,
                                                const float* __restrict__ scw,
                                                const float* __restrict__ scb,
                                                float* __restrict__ regsc) {
    __shared__ float Ws[FCD * 16];   // 32 KB
    int t = threadIdx.x;
    int m0 = blockIdx.x * 16;
    for (int e = t; e < FCD * 16; e += 256) {
        int k = e >> 4, j = e & 15;
        float v = 0.f;
        if (j < 12) v = regw[k * 12 + j];
        else if (j < 15) v = scw[k * 3 + (j - 12)];
        Ws[e] = v;
    }
    __syncthreads();
    int ml = t >> 4, j = t & 15;
    const float* y = Y2 + (size_t)(m0 + ml) * FCD;
    float s = 0.f;
    #pragma unroll 4
    for (int k4 = 0; k4 < FCD / 4; k4++) {
        float4 yv = *(const float4*)(y + k4 * 4);
        s += yv.x * Ws[(k4 * 4 + 0) * 16 + j]
           + yv.y * Ws[(k4 * 4 + 1) * 16 + j]
           + yv.z * Ws[(k4 * 4 + 2) * 16 + j]
           + yv.w * Ws[(k4 * 4 + 3) * 16 + j];
    }
    if (j < 12)      regsc[(m0 + ml) * 16 + j] = s + regb[j];
    else if (j < 15) regsc[(m0 + ml) * 16 + j] = s + scb[j - 12];
}

// ---------------- K7: class gather + recover boxes ----------------
__global__ void finalize_k(const float* __restrict__ regsc, const int* __restrict__ cls,
                           float* __restrict__ out) {
    int m = blockIdx.x * 256 + threadIdx.x;
    if (m >= MT) return;
    int c = cls[m >> 8];
    float r0 = regsc[m * 16 + c * 4 + 0];
    float r1 = regsc[m * 16 + c * 4 + 1];
    float r2 = regsc[m * 16 + c * 4 + 2];
    float r3 = regsc[m * 16 + c * 4 + 3];
    float sc = regsc[m * 16 + 12 + c];
    float* reg_out = out + 8192;
    float* sc_out  = out + 16384;
    float* rb_out  = out + 18432;
    reg_out[4 * m + 0] = r0;
    reg_out[4 * m + 1] = r1;
    reg_out[4 * m + 2] = r2;
    reg_out[4 * m + 3] = r3;
    sc_out[m] = sc;
    const float* nb = out;
    float v0 = nb[4 * m + 0], v1 = nb[4 * m + 1], v2 = nb[4 * m + 2], v3 = nb[4 * m + 3];
    float bh = v2 - v0, bw = v3 - v1;
    float bcy = (v0 + v2) * 0.5f, bcx = (v1 + v3) * 0.5f;
    float ncy = bcy + r0 * bh;
    float ncx = bcx + r1 * bw;
    float nh = bh * expf(r2);
    float nw = bw * expf(r3);
    rb_out[4 * m + 0] = ncy - nh * 0.5f;
    rb_out[4 * m + 1] = ncx - nw * 0.5f;
    rb_out[4 * m + 2] = ncy + nh * 0.5f;
    rb_out[4 * m + 3] = ncx + nw * 0.5f;
}

extern "C" void kernel_launch(void* const* d_in, const int* in_sizes, int n_in,
                              void* d_out, int out_size, void* d_ws, size_t ws_size,
                              hipStream_t stream) {
    const float* feat = (const float*)d_in[0];
    const int*   lab  = (const int*)d_in[1];
    const float* szm  = (const float*)d_in[2];
    const float* wtm  = (const float*)d_in[3];
    const int*   cls  = (const int*)d_in[4];
    const float* w1   = (const float*)d_in[5];
    const float* b1   = (const float*)d_in[6];
    const float* w2   = (const float*)d_in[7];
    const float* b2   = (const float*)d_in[8];
    const float* fc1w = (const float*)d_in[9];
    const float* fc1b = (const float*)d_in[10];
    const float* fc2w = (const float*)d_in[11];
    const float* fc2b = (const float*)d_in[12];
    const float* regw = (const float*)d_in[13];
    const float* regb = (const float*)d_in[14];
    const float* scw  = (const float*)d_in[15];
    const float* scb  = (const float*)d_in[16];
    float* out = (float*)d_out;

    char* w = (char*)d_ws;
    int*   seg_i = (int*)w;                              // 32 KB
    float* seg_f = (float*)(w + 32768);                  // 32 KB
    short* cropH = (short*)(w + 65536);                  // 2048*256*32 shorts
    short* cropL = cropH + (size_t)MT * 256 * 32;
    short* c1H   = cropL + (size_t)MT * 256 * 32;        // 2048*64*64
    short* c1L   = c1H + (size_t)MT * 64 * 64;
    short* XH    = c1L + (size_t)MT * 64 * 64;           // 2048*16*128
    short* XL    = XH + (size_t)MT * 16 * 128;
    short* Y1H   = XL + (size_t)MT * 16 * 128;           // 2048*512
    short* Y1L   = Y1H + (size_t)MT * FCD;
    float* Y2    = (float*)(Y1L + (size_t)MT * FCD);     // 4 MB fp32
    float* regsc = Y2 + (size_t)MT * FCD;                // 2048*16

    init_k<<<32, 256, 0, stream>>>(seg_i, seg_f);
    segreduce_k<<<NB * 64, 256, 0, stream>>>(lab, szm, wtm, seg_i, seg_f);
    boxes_k<<<MT / 256, 256, 0, stream>>>(seg_i, seg_f, out);
    crop_k<<<MT, 256, 0, stream>>>(feat, out, cropH, cropL);
    // conv1: M=131072, K=288, N=64
    gemm_k<1, 1><<<dim3(1, 2048), 256, 0, stream>>>(cropH, cropL, w1, b1,
                                                    c1H, c1L, nullptr, MT * 64, 288, 64);
    // conv2: M=32768, K=576, N=128
    gemm_k<2, 1><<<dim3(2, 512), 256, 0, stream>>>(c1H, c1L, w2, b2,
                                                   XH, XL, nullptr, MT * 16, 576, 128);
    // fc1: M=2048, K=2048, N=512
    gemm_k<0, 1><<<dim3(8, 32), 256, 0, stream>>>(XH, XL, fc1w, fc1b,
                                                  Y1H, Y1L, nullptr, MT, FLAT, FCD);
    // fc2: M=2048, K=512, N=512 (fp32 out for heads)
    gemm_k<0, 0><<<dim3(8, 32), 256, 0, stream>>>(Y1H, Y1L, fc2w, fc2b,
                                                  nullptr, nullptr, Y2, MT, FCD, FCD);
    heads2_k<<<MT / 16, 256, 0, stream>>>(Y2, regw, regb, scw, scb, regsc);
    finalize_k<<<MT / 256, 256, 0, stream>>>(regsc, cls, out);
}